// Round 1
// baseline (1189.395 us; speedup 1.0000x reference)
//
#include <hip/hip_runtime.h>

#define N_NODES 50000
#define N_EDGES 600000
#define D 128

// ---------------------------------------------------------------------------
// GEMM: pre[n][d] = sum_k x[n][k] * W[k][d]
// block = 256 threads, 8 nodes/block, each thread: 1 node x 4 dims (float4).
// 50000 / 8 = 6250 blocks exactly (no tail).
// x rows staged in LDS (broadcast reads); W read via coalesced float4 from
// global (64 KB, fully L2-resident, reused by all blocks).
// ---------------------------------------------------------------------------
__global__ __launch_bounds__(256) void gemm_xw_kernel(
    const float* __restrict__ x, const float* __restrict__ W,
    float* __restrict__ pre) {
  const int tid = threadIdx.x;
  const int local_n = tid >> 5;        // 0..7
  const int d4 = (tid & 31) << 2;      // 0,4,...,124
  const int n = blockIdx.x * 8 + local_n;

  __shared__ float xs[8][D];
  {
    // 8 rows * 128 floats = 256 float4 loads, one per thread
    float4* xs4 = (float4*)(&xs[0][0]);
    const float4* xg4 = (const float4*)(x + (size_t)blockIdx.x * 8 * D);
    xs4[tid] = xg4[tid];
  }
  __syncthreads();

  float4 acc = make_float4(0.f, 0.f, 0.f, 0.f);
#pragma unroll 8
  for (int k = 0; k < D; ++k) {
    const float xv = xs[local_n][k];
    const float4 w = *(const float4*)(W + k * D + d4);
    acc.x = fmaf(xv, w.x, acc.x);
    acc.y = fmaf(xv, w.y, acc.y);
    acc.z = fmaf(xv, w.z, acc.z);
    acc.w = fmaf(xv, w.w, acc.w);
  }
  *(float4*)(pre + (size_t)n * D + d4) = acc;
}

// ---------------------------------------------------------------------------
// SpMM scatter: out[rows[e]][d] += vals[e] * pre[cols[e]][d]
// 64 lanes per edge, 2 dims per lane (float2 gather, 2 scalar atomics).
// ---------------------------------------------------------------------------
__global__ __launch_bounds__(256) void spmm_scatter_kernel(
    const int* __restrict__ rows, const int* __restrict__ cols,
    const float* __restrict__ vals, const float* __restrict__ pre,
    float* __restrict__ out) {
  const long long idx = (long long)blockIdx.x * blockDim.x + threadIdx.x;
  const int e = (int)(idx >> 6);  // 64 threads per edge
  if (e >= N_EDGES) return;
  const int dd = ((int)idx & 63) << 1;  // 0,2,...,126
  const int r = rows[e];
  const int c = cols[e];
  const float v = vals[e];
  const float2 p = *(const float2*)(pre + (size_t)c * D + dd);
  float* outp = out + (size_t)r * D + dd;
  atomicAdd(outp + 0, v * p.x);
  atomicAdd(outp + 1, v * p.y);
}

// ---------------------------------------------------------------------------
// out = relu(out + b), vectorized float4. N*D/4 = 1.6M elems, 6250 blocks.
// ---------------------------------------------------------------------------
__global__ __launch_bounds__(256) void bias_relu_kernel(
    float* __restrict__ out, const float* __restrict__ b) {
  const int idx = blockIdx.x * blockDim.x + threadIdx.x;  // over N*D/4
  float4 v = ((float4*)out)[idx];
  const float4 bb = ((const float4*)b)[idx & 31];  // D/4 = 32 float4 per row
  v.x = fmaxf(v.x + bb.x, 0.f);
  v.y = fmaxf(v.y + bb.y, 0.f);
  v.z = fmaxf(v.z + bb.z, 0.f);
  v.w = fmaxf(v.w + bb.w, 0.f);
  ((float4*)out)[idx] = v;
}

extern "C" void kernel_launch(void* const* d_in, const int* in_sizes, int n_in,
                              void* d_out, int out_size, void* d_ws,
                              size_t ws_size, hipStream_t stream) {
  const float* x = (const float*)d_in[0];
  const float* W0 = (const float*)d_in[1];
  const float* W1 = (const float*)d_in[2];
  const float* b = (const float*)d_in[3];
  const int* rows0 = (const int*)d_in[4];
  const int* cols0 = (const int*)d_in[5];
  const float* vals0 = (const float*)d_in[6];
  const int* rows1 = (const int*)d_in[7];
  const int* cols1 = (const int*)d_in[8];
  const float* vals1 = (const float*)d_in[9];

  float* out = (float*)d_out;
  float* pre = (float*)d_ws;  // 50000*128*4 = 25.6 MB scratch

  hipMemsetAsync(d_out, 0, (size_t)N_NODES * D * sizeof(float), stream);

  const int gemm_blocks = N_NODES / 8;                    // 6250
  const int scat_blocks = (N_EDGES * 64 + 255) / 256;     // 150000

  // support 0
  gemm_xw_kernel<<<gemm_blocks, 256, 0, stream>>>(x, W0, pre);
  spmm_scatter_kernel<<<scat_blocks, 256, 0, stream>>>(rows0, cols0, vals0,
                                                       pre, out);
  // support 1 (reuses ws; stream order serializes with scatter 0)
  gemm_xw_kernel<<<gemm_blocks, 256, 0, stream>>>(x, W1, pre);
  spmm_scatter_kernel<<<scat_blocks, 256, 0, stream>>>(rows1, cols1, vals1,
                                                       pre, out);

  bias_relu_kernel<<<(N_NODES * D / 4) / 256, 256, 0, stream>>>(out, b);
}

// Round 2
// 474.075 us; speedup vs baseline: 2.5089x; 2.5089x over previous
//
#include <hip/hip_runtime.h>

#define N_NODES 50000
#define N_EDGES 600000
#define D 128

// ============================================================================
// GEMM: pre[n][d] = sum_k x[n][k] * W[k][d]
// 32 nodes/block, 256 threads: thread = 4 nodes x 4 dims (16 outputs).
// x rows staged in LDS (broadcast reads), W float4 from global (L1/L2).
// ============================================================================
__global__ __launch_bounds__(256) void gemm_xw_kernel(
    const float* __restrict__ x, const float* __restrict__ W,
    float* __restrict__ pre) {
  const int tid = threadIdx.x;
  const int ln = (tid >> 5) << 2;   // node group base: 0,4,...,28
  const int d4 = (tid & 31) << 2;   // dim base: 0,4,...,124
  const int nbase = blockIdx.x * 32;

  __shared__ float xs[32][D];
  {
    float4* xs4 = (float4*)(&xs[0][0]);
    const float4* xg4 = (const float4*)x;
    for (int i = tid; i < 32 * (D / 4); i += 256) {
      const int row = nbase + (i >> 5);
      xs4[i] = (row < N_NODES) ? xg4[(size_t)row * (D / 4) + (i & 31)]
                               : make_float4(0.f, 0.f, 0.f, 0.f);
    }
  }
  __syncthreads();

  float4 a0 = make_float4(0.f, 0.f, 0.f, 0.f), a1 = a0, a2 = a0, a3 = a0;
#pragma unroll 4
  for (int k = 0; k < D; ++k) {
    const float4 w = *(const float4*)(W + k * D + d4);
    const float x0 = xs[ln + 0][k];
    const float x1 = xs[ln + 1][k];
    const float x2 = xs[ln + 2][k];
    const float x3 = xs[ln + 3][k];
    a0.x = fmaf(x0, w.x, a0.x); a0.y = fmaf(x0, w.y, a0.y);
    a0.z = fmaf(x0, w.z, a0.z); a0.w = fmaf(x0, w.w, a0.w);
    a1.x = fmaf(x1, w.x, a1.x); a1.y = fmaf(x1, w.y, a1.y);
    a1.z = fmaf(x1, w.z, a1.z); a1.w = fmaf(x1, w.w, a1.w);
    a2.x = fmaf(x2, w.x, a2.x); a2.y = fmaf(x2, w.y, a2.y);
    a2.z = fmaf(x2, w.z, a2.z); a2.w = fmaf(x2, w.w, a2.w);
    a3.x = fmaf(x3, w.x, a3.x); a3.y = fmaf(x3, w.y, a3.y);
    a3.z = fmaf(x3, w.z, a3.z); a3.w = fmaf(x3, w.w, a3.w);
  }

  float* outp = pre + (size_t)(nbase + ln) * D + d4;
  if (nbase + ln + 0 < N_NODES) *(float4*)(outp + 0 * D) = a0;
  if (nbase + ln + 1 < N_NODES) *(float4*)(outp + 1 * D) = a1;
  if (nbase + ln + 2 < N_NODES) *(float4*)(outp + 2 * D) = a2;
  if (nbase + ln + 3 < N_NODES) *(float4*)(outp + 3 * D) = a3;
}

// ============================================================================
// CSR build: histogram -> scan -> slot scatter
// ============================================================================
__global__ __launch_bounds__(256) void hist_kernel(const int* __restrict__ rows,
                                                   int* __restrict__ cnt) {
  const int e = blockIdx.x * 256 + threadIdx.x;
  if (e < N_EDGES) atomicAdd(&cnt[rows[e]], 1);
}

// Single block of 1024 threads: chunked serial sums + Hillis-Steele block scan.
__global__ __launch_bounds__(1024) void scan_kernel(const int* __restrict__ cnt,
                                                    int* __restrict__ row_start) {
  __shared__ int sums[1024];
  const int t = threadIdx.x;
  const int CH = (N_NODES + 1023) / 1024;  // 49
  const int base = t * CH;
  const int end = min(base + CH, N_NODES);
  int s = 0;
  for (int i = base; i < end; ++i) s += cnt[i];
  sums[t] = s;
  __syncthreads();
  for (int off = 1; off < 1024; off <<= 1) {
    const int v = sums[t];
    const int u = (t >= off) ? sums[t - off] : 0;
    __syncthreads();
    sums[t] = v + u;
    __syncthreads();
  }
  int excl = (t == 0) ? 0 : sums[t - 1];
  for (int i = base; i < end; ++i) {
    row_start[i] = excl;
    excl += cnt[i];
  }
  if (t == 1023) row_start[N_NODES] = sums[1023];
}

__global__ __launch_bounds__(256) void csr_fill_kernel(
    const int* __restrict__ rows, const int* __restrict__ cols,
    const float* __restrict__ vals, const int* __restrict__ row_start,
    int* __restrict__ fill, int* __restrict__ ccols, float* __restrict__ cvals) {
  const int e = blockIdx.x * 256 + threadIdx.x;
  if (e >= N_EDGES) return;
  const int r = rows[e];
  const int p = row_start[r] + atomicAdd(&fill[r], 1);
  ccols[p] = cols[e];
  cvals[p] = vals[e];
}

// ============================================================================
// CSR SpMM gather: one wave per output row, lane holds 2 dims (float2).
// Edge (col,val) loaded coalesced 64-at-a-time, broadcast via shfl.
// Pass A: out = s0. Pass B: out = relu(out + s1 + b).
// ============================================================================
template <int PASS>
__global__ __launch_bounds__(256) void spmm_csr_kernel(
    const int* __restrict__ row_start, const int* __restrict__ ccols,
    const float* __restrict__ cvals, const float* __restrict__ pre,
    const float* __restrict__ bias, float* __restrict__ out) {
  const int wid = blockIdx.x * 4 + (threadIdx.x >> 6);  // row; grid 12500 exact
  const int lane = threadIdx.x & 63;
  const int dd = lane << 1;
  const int s = row_start[wid];
  const int e = row_start[wid + 1];

  float2 acc = make_float2(0.f, 0.f);
  for (int j = s; j < e; j += 64) {
    const int nb = min(64, e - j);
    int c = 0;
    float v = 0.f;
    if (lane < nb) {
      c = ccols[j + lane];
      v = cvals[j + lane];
    }
    for (int t = 0; t < nb; ++t) {
      const int ct = __shfl(c, t);
      const float vt = __shfl(v, t);
      const float2 p = *(const float2*)(pre + (size_t)ct * D + dd);
      acc.x = fmaf(vt, p.x, acc.x);
      acc.y = fmaf(vt, p.y, acc.y);
    }
  }

  float* op = out + (size_t)wid * D + dd;
  if (PASS == 0) {
    *(float2*)op = acc;
  } else {
    const float2 prev = *(const float2*)op;
    const float2 bb = *(const float2*)(bias + dd);
    float2 r;
    r.x = fmaxf(prev.x + acc.x + bb.x, 0.f);
    r.y = fmaxf(prev.y + acc.y + bb.y, 0.f);
    *(float2*)op = r;
  }
}

// ============================================================================
// Fallback (round-1 path) if workspace is too small for CSR build
// ============================================================================
__global__ __launch_bounds__(256) void spmm_scatter_kernel(
    const int* __restrict__ rows, const int* __restrict__ cols,
    const float* __restrict__ vals, const float* __restrict__ pre,
    float* __restrict__ out) {
  const long long idx = (long long)blockIdx.x * blockDim.x + threadIdx.x;
  const int e = (int)(idx >> 6);
  if (e >= N_EDGES) return;
  const int dd = ((int)idx & 63) << 1;
  const int r = rows[e];
  const int c = cols[e];
  const float v = vals[e];
  const float2 p = *(const float2*)(pre + (size_t)c * D + dd);
  float* outp = out + (size_t)r * D + dd;
  atomicAdd(outp + 0, v * p.x);
  atomicAdd(outp + 1, v * p.y);
}

__global__ __launch_bounds__(256) void bias_relu_kernel(
    float* __restrict__ out, const float* __restrict__ b) {
  const int idx = blockIdx.x * blockDim.x + threadIdx.x;
  float4 v = ((float4*)out)[idx];
  const float4 bb = ((const float4*)b)[idx & 31];
  v.x = fmaxf(v.x + bb.x, 0.f);
  v.y = fmaxf(v.y + bb.y, 0.f);
  v.z = fmaxf(v.z + bb.z, 0.f);
  v.w = fmaxf(v.w + bb.w, 0.f);
  ((float4*)out)[idx] = v;
}

extern "C" void kernel_launch(void* const* d_in, const int* in_sizes, int n_in,
                              void* d_out, int out_size, void* d_ws,
                              size_t ws_size, hipStream_t stream) {
  const float* x = (const float*)d_in[0];
  const float* W0 = (const float*)d_in[1];
  const float* W1 = (const float*)d_in[2];
  const float* b = (const float*)d_in[3];
  const int* rows0 = (const int*)d_in[4];
  const int* cols0 = (const int*)d_in[5];
  const float* vals0 = (const float*)d_in[6];
  const int* rows1 = (const int*)d_in[7];
  const int* cols1 = (const int*)d_in[8];
  const float* vals1 = (const float*)d_in[9];
  float* out = (float*)d_out;

  // workspace layout
  const size_t PRE_BYTES = (size_t)N_NODES * D * sizeof(float);   // 25,600,000
  const size_t RS_BYTES = ((size_t)(N_NODES + 1) * 4 + 63) & ~63; // row_start
  const size_t CNT_BYTES = ((size_t)N_NODES * 4 + 63) & ~63;      // cnt/fill
  const size_t CC_BYTES = (size_t)N_EDGES * 4;                    // csr cols
  const size_t CV_BYTES = (size_t)N_EDGES * 4;                    // csr vals
  const size_t NEED = PRE_BYTES + RS_BYTES + CNT_BYTES + CC_BYTES + CV_BYTES;

  char* wsc = (char*)d_ws;
  float* pre = (float*)wsc;

  const int gemm_blocks = (N_NODES + 31) / 32;     // 1563
  const int edge_blocks = (N_EDGES + 255) / 256;   // 2344

  if (ws_size >= NEED) {
    int* row_start = (int*)(wsc + PRE_BYTES);
    int* cnt = (int*)(wsc + PRE_BYTES + RS_BYTES);
    int* ccols = (int*)(wsc + PRE_BYTES + RS_BYTES + CNT_BYTES);
    float* cvals = (float*)(wsc + PRE_BYTES + RS_BYTES + CNT_BYTES + CC_BYTES);

    const int* rr[2] = {rows0, rows1};
    const int* cc[2] = {cols0, cols1};
    const float* vv[2] = {vals0, vals1};
    const float* WW[2] = {W0, W1};

    for (int sup = 0; sup < 2; ++sup) {
      // CSR build
      hipMemsetAsync(cnt, 0, (size_t)N_NODES * 4, stream);
      hist_kernel<<<edge_blocks, 256, 0, stream>>>(rr[sup], cnt);
      scan_kernel<<<1, 1024, 0, stream>>>(cnt, row_start);
      hipMemsetAsync(cnt, 0, (size_t)N_NODES * 4, stream);
      csr_fill_kernel<<<edge_blocks, 256, 0, stream>>>(
          rr[sup], cc[sup], vv[sup], row_start, cnt, ccols, cvals);
      // dense pre-multiply
      gemm_xw_kernel<<<gemm_blocks, 256, 0, stream>>>(x, WW[sup], pre);
      // gather SpMM
      if (sup == 0)
        spmm_csr_kernel<0><<<N_NODES / 4, 256, 0, stream>>>(
            row_start, ccols, cvals, pre, b, out);
      else
        spmm_csr_kernel<1><<<N_NODES / 4, 256, 0, stream>>>(
            row_start, ccols, cvals, pre, b, out);
    }
  } else {
    // fallback: atomic scatter path
    hipMemsetAsync(d_out, 0, PRE_BYTES, stream);
    const int scat_blocks = (N_EDGES * 64 + 255) / 256;
    gemm_xw_kernel<<<gemm_blocks, 256, 0, stream>>>(x, W0, pre);
    spmm_scatter_kernel<<<scat_blocks, 256, 0, stream>>>(rows0, cols0, vals0,
                                                         pre, out);
    gemm_xw_kernel<<<gemm_blocks, 256, 0, stream>>>(x, W1, pre);
    spmm_scatter_kernel<<<scat_blocks, 256, 0, stream>>>(rows1, cols1, vals1,
                                                         pre, out);
    bias_relu_kernel<<<(N_NODES * D / 4) / 256, 256, 0, stream>>>(out, b);
  }
}

// Round 3
// 279.172 us; speedup vs baseline: 4.2604x; 1.6981x over previous
//
#include <hip/hip_runtime.h>

#define N_NODES 50000
#define N_EDGES 600000
#define D 128
#define NBLK_NODES 196   // ceil(50000/256)
#define NBLK_EDGES 2344  // ceil(600000/256)

// ============================================================================
// GEMM: pre[n][d] = sum_k x[n][k] * W[k][d]
// 64 nodes/block, 256 threads: thread = 8 nodes x 4 dims (32 outputs).
// k tiled by 4: 4 W float4 loads + 8 xs float4 LDS reads -> 128 FMA.
// ============================================================================
__global__ __launch_bounds__(256) void gemm_xw_kernel(
    const float* __restrict__ x, const float* __restrict__ W,
    float* __restrict__ pre) {
  const int tid = threadIdx.x;
  const int nloc = (tid >> 5) << 3;  // local node base 0,8,...,56
  const int d4 = (tid & 31) << 2;    // dim base 0,4,...,124
  const int nbase = blockIdx.x * 64;

  __shared__ float xs[64][D];
  {
    float4* xs4 = (float4*)(&xs[0][0]);
    const float4* xg4 = (const float4*)x;
#pragma unroll
    for (int i = 0; i < 8; ++i) {
      const int idx = tid + i * 256;  // 0..2047 covers 64 rows x 32 float4
      const int row = nbase + (idx >> 5);
      xs4[idx] = (row < N_NODES) ? xg4[(size_t)row * 32 + (idx & 31)]
                                 : make_float4(0.f, 0.f, 0.f, 0.f);
    }
  }
  __syncthreads();

  float4 acc[8];
#pragma unroll
  for (int i = 0; i < 8; ++i) acc[i] = make_float4(0.f, 0.f, 0.f, 0.f);

  for (int k = 0; k < D; k += 4) {
    float4 w[4];
#pragma unroll
    for (int kk = 0; kk < 4; ++kk)
      w[kk] = *(const float4*)(W + (k + kk) * D + d4);
#pragma unroll
    for (int i = 0; i < 8; ++i) {
      const float4 xv = *(const float4*)(&xs[nloc + i][k]);
      acc[i].x = fmaf(xv.x, w[0].x, acc[i].x);
      acc[i].y = fmaf(xv.x, w[0].y, acc[i].y);
      acc[i].z = fmaf(xv.x, w[0].z, acc[i].z);
      acc[i].w = fmaf(xv.x, w[0].w, acc[i].w);
      acc[i].x = fmaf(xv.y, w[1].x, acc[i].x);
      acc[i].y = fmaf(xv.y, w[1].y, acc[i].y);
      acc[i].z = fmaf(xv.y, w[1].z, acc[i].z);
      acc[i].w = fmaf(xv.y, w[1].w, acc[i].w);
      acc[i].x = fmaf(xv.z, w[2].x, acc[i].x);
      acc[i].y = fmaf(xv.z, w[2].y, acc[i].y);
      acc[i].z = fmaf(xv.z, w[2].z, acc[i].z);
      acc[i].w = fmaf(xv.z, w[2].w, acc[i].w);
      acc[i].x = fmaf(xv.w, w[3].x, acc[i].x);
      acc[i].y = fmaf(xv.w, w[3].y, acc[i].y);
      acc[i].z = fmaf(xv.w, w[3].z, acc[i].z);
      acc[i].w = fmaf(xv.w, w[3].w, acc[i].w);
    }
  }
#pragma unroll
  for (int i = 0; i < 8; ++i) {
    const int n = nbase + nloc + i;
    if (n < N_NODES) *(float4*)(pre + (size_t)n * D + d4) = acc[i];
  }
}

// ============================================================================
// CSR build: hist (grid.y = support) -> hierarchical scan -> slot fill
// ============================================================================
__global__ __launch_bounds__(256) void hist2_kernel(
    const int* __restrict__ rowsA, const int* __restrict__ rowsB,
    int* __restrict__ cnt) {
  const int e = blockIdx.x * 256 + threadIdx.x;
  if (e >= N_EDGES) return;
  const int sup = blockIdx.y;
  const int r = (sup == 0 ? rowsA : rowsB)[e];
  atomicAdd(&cnt[sup * N_NODES + r], 1);
}

// per-block sums
__global__ __launch_bounds__(256) void scan1_kernel(const int* __restrict__ cnt,
                                                    int* __restrict__ bsum) {
  const int sup = blockIdx.y;
  const int i = blockIdx.x * 256 + threadIdx.x;
  __shared__ int sh[256];
  sh[threadIdx.x] = (i < N_NODES) ? cnt[sup * N_NODES + i] : 0;
  __syncthreads();
  for (int off = 128; off > 0; off >>= 1) {
    if (threadIdx.x < off) sh[threadIdx.x] += sh[threadIdx.x + off];
    __syncthreads();
  }
  if (threadIdx.x == 0) bsum[sup * NBLK_NODES + blockIdx.x] = sh[0];
}

// exclusive scan of the NBLK_NODES block sums, per support (1 block total)
__global__ __launch_bounds__(256) void scan2_kernel(int* __restrict__ bsum,
                                                    int nsup) {
  __shared__ int sh[256];
  const int t = threadIdx.x;
  for (int sup = 0; sup < nsup; ++sup) {
    const int v = (t < NBLK_NODES) ? bsum[sup * NBLK_NODES + t] : 0;
    sh[t] = v;
    __syncthreads();
    for (int off = 1; off < 256; off <<= 1) {
      const int u = (t >= off) ? sh[t - off] : 0;
      __syncthreads();
      sh[t] += u;
      __syncthreads();
    }
    if (t < NBLK_NODES) bsum[sup * NBLK_NODES + t] = sh[t] - v;  // exclusive
    __syncthreads();
  }
}

// block-local exclusive scan + block offset -> row_start
__global__ __launch_bounds__(256) void scan3_kernel(
    const int* __restrict__ cnt, const int* __restrict__ bsum,
    int* __restrict__ rs) {
  const int sup = blockIdx.y;
  const int t = threadIdx.x;
  const int i = blockIdx.x * 256 + t;
  __shared__ int sh[256];
  const int v = (i < N_NODES) ? cnt[sup * N_NODES + i] : 0;
  sh[t] = v;
  __syncthreads();
  for (int off = 1; off < 256; off <<= 1) {
    const int u = (t >= off) ? sh[t - off] : 0;
    __syncthreads();
    sh[t] += u;
    __syncthreads();
  }
  const int boff = bsum[sup * NBLK_NODES + blockIdx.x];
  if (i < N_NODES) rs[sup * (N_NODES + 1) + i] = boff + sh[t] - v;
  if (blockIdx.x == NBLK_NODES - 1 && t == 255)
    rs[sup * (N_NODES + 1) + N_NODES] = boff + sh[255];
}

__global__ __launch_bounds__(256) void fill2_kernel(
    const int* __restrict__ rowsA, const int* __restrict__ colsA,
    const float* __restrict__ valsA, const int* __restrict__ rowsB,
    const int* __restrict__ colsB, const float* __restrict__ valsB,
    const int* __restrict__ rs, int* __restrict__ fillc,
    int2* __restrict__ cv) {
  const int e = blockIdx.x * 256 + threadIdx.x;
  if (e >= N_EDGES) return;
  const int sup = blockIdx.y;
  const int* rows = (sup == 0) ? rowsA : rowsB;
  const int* cols = (sup == 0) ? colsA : colsB;
  const float* vals = (sup == 0) ? valsA : valsB;
  const int r = rows[e];
  const int p =
      rs[sup * (N_NODES + 1) + r] + atomicAdd(&fillc[sup * N_NODES + r], 1);
  cv[(size_t)sup * N_EDGES + p] = make_int2(cols[e], __float_as_int(vals[e]));
}

// ============================================================================
// CSR SpMM gather: one wave/row; 4 edge-groups x 16 dim-lanes x 8 dims.
// Pass 0: out = s0. Pass 1: out = relu(out + s1 + b).
// ============================================================================
template <int PASS>
__global__ __launch_bounds__(256) void spmm_csr_kernel(
    const int* __restrict__ row_start, const int2* __restrict__ cv,
    const float* __restrict__ pre, const float* __restrict__ bias,
    float* __restrict__ out) {
  const int row = blockIdx.x * 4 + (threadIdx.x >> 6);
  const int lane = threadIdx.x & 63;
  const int g = lane >> 4;            // edge group 0..3
  const int dbase = (lane & 15) << 3; // 8 dims per lane
  const int s = row_start[row];
  const int e = row_start[row + 1];

  float4 a0 = make_float4(0.f, 0.f, 0.f, 0.f);
  float4 a1 = make_float4(0.f, 0.f, 0.f, 0.f);
  for (int j = s; j < e; j += 64) {
    const int nb = min(64, e - j);
    int c = 0;
    float v = 0.f;
    if (lane < nb) {
      const int2 p = cv[j + lane];
      c = p.x;
      v = __int_as_float(p.y);
    }
    for (int t4 = 0; t4 < nb; t4 += 4) {
      const int t = t4 + g;
      const int ct = __shfl(c, t & 63);
      const float vt = __shfl(v, t & 63);
      if (t < nb) {
        const float4* p = (const float4*)(pre + (size_t)ct * D + dbase);
        const float4 p0 = p[0];
        const float4 p1 = p[1];
        a0.x = fmaf(vt, p0.x, a0.x);
        a0.y = fmaf(vt, p0.y, a0.y);
        a0.z = fmaf(vt, p0.z, a0.z);
        a0.w = fmaf(vt, p0.w, a0.w);
        a1.x = fmaf(vt, p1.x, a1.x);
        a1.y = fmaf(vt, p1.y, a1.y);
        a1.z = fmaf(vt, p1.z, a1.z);
        a1.w = fmaf(vt, p1.w, a1.w);
      }
    }
  }
  // reduce across the 4 edge groups (lanes ^16, ^32)
#pragma unroll
  for (int off = 16; off <= 32; off <<= 1) {
    a0.x += __shfl_xor(a0.x, off);
    a0.y += __shfl_xor(a0.y, off);
    a0.z += __shfl_xor(a0.z, off);
    a0.w += __shfl_xor(a0.w, off);
    a1.x += __shfl_xor(a1.x, off);
    a1.y += __shfl_xor(a1.y, off);
    a1.z += __shfl_xor(a1.z, off);
    a1.w += __shfl_xor(a1.w, off);
  }
  if (g == 0) {
    float* op = out + (size_t)row * D + dbase;
    if (PASS == 0) {
      *(float4*)op = a0;
      *(float4*)(op + 4) = a1;
    } else {
      float4 q0 = *(const float4*)op;
      float4 q1 = *(const float4*)(op + 4);
      const float4 b0 = *(const float4*)(bias + dbase);
      const float4 b1 = *(const float4*)(bias + dbase + 4);
      q0.x = fmaxf(q0.x + a0.x + b0.x, 0.f);
      q0.y = fmaxf(q0.y + a0.y + b0.y, 0.f);
      q0.z = fmaxf(q0.z + a0.z + b0.z, 0.f);
      q0.w = fmaxf(q0.w + a0.w + b0.w, 0.f);
      q1.x = fmaxf(q1.x + a1.x + b1.x, 0.f);
      q1.y = fmaxf(q1.y + a1.y + b1.y, 0.f);
      q1.z = fmaxf(q1.z + a1.z + b1.z, 0.f);
      q1.w = fmaxf(q1.w + a1.w + b1.w, 0.f);
      *(float4*)op = q0;
      *(float4*)(op + 4) = q1;
    }
  }
}

// ============================================================================
// Fallback: atomic scatter path (used only if workspace too small)
// ============================================================================
__global__ __launch_bounds__(256) void spmm_scatter_kernel(
    const int* __restrict__ rows, const int* __restrict__ cols,
    const float* __restrict__ vals, const float* __restrict__ pre,
    float* __restrict__ out) {
  const long long idx = (long long)blockIdx.x * blockDim.x + threadIdx.x;
  const int e = (int)(idx >> 6);
  if (e >= N_EDGES) return;
  const int dd = ((int)idx & 63) << 1;
  const int r = rows[e];
  const int c = cols[e];
  const float v = vals[e];
  const float2 p = *(const float2*)(pre + (size_t)c * D + dd);
  float* outp = out + (size_t)r * D + dd;
  atomicAdd(outp + 0, v * p.x);
  atomicAdd(outp + 1, v * p.y);
}

__global__ __launch_bounds__(256) void bias_relu_kernel(
    float* __restrict__ out, const float* __restrict__ b) {
  const int idx = blockIdx.x * blockDim.x + threadIdx.x;
  float4 v = ((float4*)out)[idx];
  const float4 bb = ((const float4*)b)[idx & 31];
  v.x = fmaxf(v.x + bb.x, 0.f);
  v.y = fmaxf(v.y + bb.y, 0.f);
  v.z = fmaxf(v.z + bb.z, 0.f);
  v.w = fmaxf(v.w + bb.w, 0.f);
  ((float4*)out)[idx] = v;
}

extern "C" void kernel_launch(void* const* d_in, const int* in_sizes, int n_in,
                              void* d_out, int out_size, void* d_ws,
                              size_t ws_size, hipStream_t stream) {
  const float* x = (const float*)d_in[0];
  const float* W0 = (const float*)d_in[1];
  const float* W1 = (const float*)d_in[2];
  const float* b = (const float*)d_in[3];
  const int* rows0 = (const int*)d_in[4];
  const int* cols0 = (const int*)d_in[5];
  const float* vals0 = (const float*)d_in[6];
  const int* rows1 = (const int*)d_in[7];
  const int* cols1 = (const int*)d_in[8];
  const float* vals1 = (const float*)d_in[9];
  float* out = (float*)d_out;

  auto align_up = [](size_t v) { return (v + 255) & ~(size_t)255; };
  const size_t PRE = align_up((size_t)N_NODES * D * 4);  // 25,600,000
  const size_t CNT1 = align_up((size_t)N_NODES * 4);
  const size_t RS1 = align_up((size_t)(N_NODES + 1) * 4);
  const size_t CV1 = align_up((size_t)N_EDGES * 8);
  const size_t BSUM2 = align_up((size_t)2 * NBLK_NODES * 4);

  char* wsc = (char*)d_ws;
  float* pre = (float*)wsc;

  const int gemm_blocks = (N_NODES + 63) / 64;  // 782
  const size_t NEED_FUSED = PRE + 2 * CNT1 + 2 * RS1 + 2 * CV1 + BSUM2;
  const size_t NEED_SEQ = PRE + CNT1 + RS1 + CV1 + BSUM2;

  if (ws_size >= NEED_FUSED) {
    int* cnt = (int*)(wsc + PRE);
    int* rs = (int*)(wsc + PRE + 2 * CNT1);
    int2* cv = (int2*)(wsc + PRE + 2 * CNT1 + 2 * RS1);
    int* bsum = (int*)(wsc + PRE + 2 * CNT1 + 2 * RS1 + 2 * CV1);

    hipMemsetAsync(cnt, 0, (size_t)2 * N_NODES * 4, stream);
    hist2_kernel<<<dim3(NBLK_EDGES, 2), 256, 0, stream>>>(rows0, rows1, cnt);
    scan1_kernel<<<dim3(NBLK_NODES, 2), 256, 0, stream>>>(cnt, bsum);
    scan2_kernel<<<1, 256, 0, stream>>>(bsum, 2);
    scan3_kernel<<<dim3(NBLK_NODES, 2), 256, 0, stream>>>(cnt, bsum, rs);
    hipMemsetAsync(cnt, 0, (size_t)2 * N_NODES * 4, stream);
    fill2_kernel<<<dim3(NBLK_EDGES, 2), 256, 0, stream>>>(
        rows0, cols0, vals0, rows1, cols1, vals1, rs, cnt, cv);

    gemm_xw_kernel<<<gemm_blocks, 256, 0, stream>>>(x, W0, pre);
    spmm_csr_kernel<0><<<N_NODES / 4, 256, 0, stream>>>(rs, cv, pre, b, out);
    gemm_xw_kernel<<<gemm_blocks, 256, 0, stream>>>(x, W1, pre);
    spmm_csr_kernel<1><<<N_NODES / 4, 256, 0, stream>>>(
        rs + (N_NODES + 1), cv + N_EDGES, pre, b, out);
  } else if (ws_size >= NEED_SEQ) {
    int* cnt = (int*)(wsc + PRE);
    int* rs = (int*)(wsc + PRE + CNT1);
    int2* cv = (int2*)(wsc + PRE + CNT1 + RS1);
    int* bsum = (int*)(wsc + PRE + CNT1 + RS1 + CV1);
    const int* rr[2] = {rows0, rows1};
    const int* cc[2] = {cols0, cols1};
    const float* vv[2] = {vals0, vals1};
    const float* WW[2] = {W0, W1};
    for (int sup = 0; sup < 2; ++sup) {
      hipMemsetAsync(cnt, 0, (size_t)N_NODES * 4, stream);
      hist2_kernel<<<dim3(NBLK_EDGES, 1), 256, 0, stream>>>(rr[sup], rr[sup],
                                                            cnt);
      scan1_kernel<<<dim3(NBLK_NODES, 1), 256, 0, stream>>>(cnt, bsum);
      scan2_kernel<<<1, 256, 0, stream>>>(bsum, 1);
      scan3_kernel<<<dim3(NBLK_NODES, 1), 256, 0, stream>>>(cnt, bsum, rs);
      hipMemsetAsync(cnt, 0, (size_t)N_NODES * 4, stream);
      fill2_kernel<<<dim3(NBLK_EDGES, 1), 256, 0, stream>>>(
          rr[sup], cc[sup], vv[sup], rr[sup], cc[sup], vv[sup], rs, cnt, cv);
      gemm_xw_kernel<<<gemm_blocks, 256, 0, stream>>>(x, WW[sup], pre);
      if (sup == 0)
        spmm_csr_kernel<0><<<N_NODES / 4, 256, 0, stream>>>(rs, cv, pre, b,
                                                            out);
      else
        spmm_csr_kernel<1><<<N_NODES / 4, 256, 0, stream>>>(rs, cv, pre, b,
                                                            out);
    }
  } else {
    hipMemsetAsync(d_out, 0, (size_t)N_NODES * D * 4, stream);
    const int scat_blocks = (N_EDGES * 64 + 255) / 256;
    gemm_xw_kernel<<<gemm_blocks, 256, 0, stream>>>(x, W0, pre);
    spmm_scatter_kernel<<<scat_blocks, 256, 0, stream>>>(rows0, cols0, vals0,
                                                         pre, out);
    gemm_xw_kernel<<<gemm_blocks, 256, 0, stream>>>(x, W1, pre);
    spmm_scatter_kernel<<<scat_blocks, 256, 0, stream>>>(rows1, cols1, vals1,
                                                         pre, out);
    bias_relu_kernel<<<(N_NODES * D / 4) / 256, 256, 0, stream>>>(out, b);
  }
}